// Round 3
// baseline (273.140 us; speedup 1.0000x reference)
//
#include <hip/hip_runtime.h>

#define NNODES 100000
#define NEDGES 3200000
#define ETOT   (NEDGES + NNODES)
#define NEG_SLOPE 0.2f

#define NPB 64                               // nodes per bucket (dst >> 6)
#define NBUCK ((NNODES + NPB - 1) / NPB)     // 1563 buckets
#define NCHUNK 256                           // edge chunks
#define CHUNK_E ((ETOT + NCHUNK - 1) / NCHUNK)  // 12891 edges/chunk
#define M2 (NBUCK * NCHUNK)                  // 400128 (chunk-scan length)
#define NSB2 ((M2 + 511) / 512)              // 782

// bf16 storage via raw ushort — no hip_fp16.h / hip_bf16.h dependency.
__device__ __forceinline__ unsigned short f2bf(float f) {
    unsigned u = __float_as_uint(f);
    u += 0x7FFFu + ((u >> 16) & 1u);         // round-to-nearest-even
    return (unsigned short)(u >> 16);
}
__device__ __forceinline__ float bf2f(unsigned short h) {
    return __uint_as_float(((unsigned)h) << 16);
}

// edge e in [0, NEDGES): src = ei[e], dst = ei[NEDGES+e]
// edge e in [NEDGES, ETOT): self-loop, src = dst = e - NEDGES
__device__ __forceinline__ void edge_sd(int e, const int* __restrict__ ei, int& s, int& d) {
    if (e < NEDGES) { s = ei[e]; d = ei[NEDGES + e]; }
    else            { s = e - NEDGES; d = s; }
}

__device__ __forceinline__ float lrelu(float v) {
    return v > 0.0f ? v : NEG_SLOPE * v;
}

// Broadcast from a compile-time lane: v_readlane -> SGPR (scalar pipe, no DS op).
__device__ __forceinline__ float bcast_lane(float v, int lane_imm) {
    return __int_as_float(__builtin_amdgcn_readlane(__float_as_int(v), lane_imm));
}

// ---------------- deterministic chunked bucket sort ----------------

__global__ void chunk_hist(const int* __restrict__ ei, int* __restrict__ H) {
    __shared__ int h[NBUCK];
    int c = blockIdx.x;
    for (int i = threadIdx.x; i < NBUCK; i += blockDim.x) h[i] = 0;
    __syncthreads();
    int lo = c * CHUNK_E, hi = lo + CHUNK_E; if (hi > ETOT) hi = ETOT;
    for (int e = lo + threadIdx.x; e < hi; e += blockDim.x) {
        int d = (e < NEDGES) ? ei[NEDGES + e] : (e - NEDGES);
        atomicAdd(&h[d >> 6], 1);
    }
    __syncthreads();
    for (int i = threadIdx.x; i < NBUCK; i += blockDim.x) H[c * NBUCK + i] = h[i];
}

// 3-phase exclusive scan of H in bucket-major order.
// Linear index i = b*NCHUNK + c (NCHUNK=256: b = i>>8, c = i&255); value = H[c*NBUCK+b].
__global__ void cscan_local(const int* __restrict__ H, int* __restrict__ off,
                            int* __restrict__ bsum2) {
    __shared__ int arr[512];
    int blk = blockIdx.x, t = threadIdx.x;
    int i = blk * 512 + t;
    int v = (i < M2) ? H[(i & (NCHUNK - 1)) * NBUCK + (i >> 8)] : 0;
    arr[t] = v;
    __syncthreads();
    for (int o = 1; o < 512; o <<= 1) {
        int u = (t >= o) ? arr[t - o] : 0;
        __syncthreads();
        arr[t] += u;
        __syncthreads();
    }
    if (i < M2) off[i] = arr[t] - v;
    if (t == 511) bsum2[blk] = arr[t];
}

__global__ void cscan_bsum(const int* __restrict__ bsum2, int* __restrict__ boff2) {
    __shared__ int arr[1024];
    int t = threadIdx.x;
    int v = (t < NSB2) ? bsum2[t] : 0;
    arr[t] = v;
    __syncthreads();
    for (int o = 1; o < 1024; o <<= 1) {
        int u = (t >= o) ? arr[t - o] : 0;
        __syncthreads();
        arr[t] += u;
        __syncthreads();
    }
    if (t < NSB2) boff2[t] = arr[t] - v;
}

__global__ void cscan_add(int* __restrict__ off, const int* __restrict__ boff2) {
    int i = blockIdx.x * 512 + threadIdx.x;
    if (i < M2) off[i] += boff2[blockIdx.x];
}

__global__ void chunk_scatter(const int* __restrict__ ei, const int* __restrict__ off,
                              int* __restrict__ pairs) {
    __shared__ int cur[NBUCK];
    int c = blockIdx.x;
    for (int b = threadIdx.x; b < NBUCK; b += blockDim.x)
        cur[b] = off[b * NCHUNK + c];
    __syncthreads();
    int lo = c * CHUNK_E, hi = lo + CHUNK_E; if (hi > ETOT) hi = ETOT;
    for (int e = lo + threadIdx.x; e < hi; e += blockDim.x) {
        int s, d; edge_sd(e, ei, s, d);
        int slot = atomicAdd(&cur[d >> 6], 1);
        pairs[slot] = ((d & 63) << 17) | s;   // src < 2^17
    }
}

__global__ void fine_sort2(const int* __restrict__ off, const int* __restrict__ pairs,
                           int* __restrict__ row_start, int* __restrict__ csr_src) {
    __shared__ int arr[NPB];
    __shared__ int cur[NPB];
    int b = blockIdx.x;
    int t = threadIdx.x;
    int base = off[b * NCHUNK];
    int bend = (b == NBUCK - 1) ? ETOT : off[(b + 1) * NCHUNK];
    if (t < NPB) arr[t] = 0;
    __syncthreads();
    for (int i = base + t; i < bend; i += blockDim.x)
        atomicAdd(&arr[pairs[i] >> 17], 1);
    __syncthreads();
    int v = (t < NPB) ? arr[t] : 0;
    __syncthreads();
    for (int o = 1; o < NPB; o <<= 1) {           // inclusive scan over 64 counts
        int u = (t < NPB && t >= o) ? arr[t - o] : 0;
        __syncthreads();
        if (t < NPB) arr[t] += u;
        __syncthreads();
    }
    if (t < NPB) {
        int node = b * NPB + t;
        int start = base + arr[t] - v;            // exclusive prefix
        cur[t] = start;
        if (node < NNODES) row_start[node] = start;
    }
    if (b == NBUCK - 1 && t == 0) row_start[NNODES] = ETOT;
    __syncthreads();
    for (int i = base + t; i < bend; i += blockDim.x) {
        int p = pairs[i];
        int slot = atomicAdd(&cur[p >> 17], 1);
        csr_src[slot] = p & 0x1FFFF;
    }
}

// ---------------- attention-vector precompute (proven) ----------------
// cvec layout: [0,1]=c1s  [2,3]=c1d  [4..19]=c2s  [20..35]=c2d
__global__ void prep(const float* __restrict__ W1, const float* __restrict__ as1,
                     const float* __restrict__ ad1, const float* __restrict__ W2,
                     const float* __restrict__ as2, const float* __restrict__ ad2,
                     float* __restrict__ cvec) {
    int t = threadIdx.x;
    if (t < 2) {
        float s = 0.f, d = 0.f;
        for (int f = 0; f < 16; ++f) { s += W1[t * 16 + f] * as1[f]; d += W1[t * 16 + f] * ad1[f]; }
        cvec[t] = s; cvec[2 + t] = d;
    }
    if (t < 16) {
        float s = 0.f, d = 0.f;
        for (int f = 0; f < 64; ++f) { s += W2[t * 64 + f] * as2[f]; d += W2[t * 64 + f] * ad2[f]; }
        cvec[4 + t] = s; cvec[20 + t] = d;
    }
}

__global__ void alpha1(const float* __restrict__ x, const float* __restrict__ cvec,
                       float* __restrict__ as_, float* __restrict__ ad_) {
    int n = blockIdx.x * blockDim.x + threadIdx.x;
    if (n >= NNODES) return;
    float2 xv = ((const float2*)x)[n];
    as_[n] = xv.x * cvec[0] + xv.y * cvec[1];
    ad_[n] = xv.x * cvec[2] + xv.y * cvec[3];
}

// ---------------- layer 1: aggregate x (2 feats), @W1 in epilogue -------------
// In-register __shfl_xor butterfly; zero LDS, zero barriers. 256-thread blocks
// (round-21: 1024 regressed — block-retire tail with degree skew).
// Round-21: (a) edge loop software-pipelined (prefetch next sj/as_/x with
// clamped index — gather chain was serial per iteration); (b) alpha2 fused
// into the epilogue: lanes hold the 16 output features, 8 more shfl_xor give
// the layer-2 alpha dot products -> separate as2/ad2 buffers (kills a kernel).
__global__ void agg_l1(const int* __restrict__ row_start, const int* __restrict__ csr_src,
                       const float* __restrict__ as_, const float* __restrict__ ad_,
                       const float* __restrict__ x, const float* __restrict__ W1,
                       const float* __restrict__ b1, const float* __restrict__ cvec,
                       unsigned short* __restrict__ g,
                       float* __restrict__ as2_, float* __restrict__ ad2_) {
    int wave = threadIdx.x >> 6, lane = threadIdx.x & 63;
    int node = blockIdx.x * 4 + wave;          // always < NNODES (exact grid)
    int base = row_start[node], end = row_start[node + 1];
    float adv = ad_[node];
    float a0 = 0.f, a1 = 0.f, ss = 0.f;
    const float2* x2 = (const float2*)x;
    int last = end - 1;                        // end > base always (self-loop)
    int i = base + lane;
    int sj = csr_src[min(i, last)];
    float asv = as_[sj];
    float2 xv = x2[sj];
    while (i < end) {
        int inext = i + 64;
        int sjn = csr_src[min(inext, last)];   // prefetch next iteration
        float asn = as_[sjn];
        float2 xn = x2[sjn];
        float w = __expf(lrelu(asv + adv));
        ss += w;
        a0 += w * xv.x;
        a1 += w * xv.y;
        i = inext; sj = sjn; asv = asn; xv = xn;
    }
#pragma unroll
    for (int m = 32; m >= 1; m >>= 1) {        // full 64-lane butterfly
        a0 += __shfl_xor(a0, m);
        a1 += __shfl_xor(a1, m);
        ss += __shfl_xor(ss, m);
    }
    int f = lane & 15;                         // all lanes compute feature f
    float v = (a0 * W1[f] + a1 * W1[16 + f]) / ss + b1[f];
    float vr = v > 0.f ? v : 0.f;
    if (lane < 16) g[node * 16 + lane] = f2bf(vr);
    // fused alpha2 (f32, closer to reference than bf16 round-trip)
    float s2 = vr * cvec[4 + f];
    float d2 = vr * cvec[20 + f];
#pragma unroll
    for (int m = 1; m <= 8; m <<= 1) {
        s2 += __shfl_xor(s2, m);
        d2 += __shfl_xor(d2, m);
    }
    if (lane == 0) { as2_[node] = s2; ad2_[node] = d2; }
}

// ---------------- layer 2: aggregate bf16 g, @W2 in epilogue ------------------
// 16 groups x 4 lanes; each lane loads a ushort4 (8B) of the 32B row -> 16 rows
// in flight. Butterfly over group bits (masks 4..32) via __shfl_xor; feature
// broadcast via v_readlane (compile-time lane). 256-thread blocks (proven).
// Round-21: edge loop software-pipelined (prefetch next sj/as_/g-row, clamped
// index) — per-iteration serial gather chain csr->as_/g was the latency floor.
__global__ void agg_l2(const int* __restrict__ row_start, const int* __restrict__ csr_src,
                       const float* __restrict__ as_, const float* __restrict__ ad_,
                       const unsigned short* __restrict__ g, const float* __restrict__ W2,
                       const float* __restrict__ b2, float* __restrict__ out) {
    int wave = threadIdx.x >> 6, lane = threadIdx.x & 63;
    int grp = lane >> 2;              // 0..15: edge group
    int q   = lane & 3;               // 0..3:  feature quad (features q*4..q*4+3)
    int node = blockIdx.x * 4 + wave; // always < NNODES (exact grid)
    int base = row_start[node], end = row_start[node + 1];
    float adv = ad_[node];
    float a0 = 0.f, a1 = 0.f, a2 = 0.f, a3 = 0.f, ss = 0.f;
    int last = end - 1;
    int i = base + grp;
    int sj = csr_src[min(i, last)];           // uniform within 4-lane group
    float asv = as_[sj];
    ushort4 hv = ((const ushort4*)(g + sj * 16))[q];
    while (i < end) {
        int inext = i + 16;
        int sjn = csr_src[min(inext, last)];  // prefetch next iteration
        float asn = as_[sjn];
        ushort4 hn = ((const ushort4*)(g + sjn * 16))[q];
        float w = __expf(lrelu(asv + adv));
        ss += w;
        a0 += w * bf2f(hv.x);
        a1 += w * bf2f(hv.y);
        a2 += w * bf2f(hv.z);
        a3 += w * bf2f(hv.w);
        i = inext; sj = sjn; asv = asn; hv = hn;
    }
    // Butterfly over group bits (masks 4,8,16,32): lane l ends with the total
    // over all 16 groups for its quad q = l&3. ss identical across lanes.
#pragma unroll
    for (int m = 4; m <= 32; m <<= 1) {
        a0 += __shfl_xor(a0, m);
        a1 += __shfl_xor(a1, m);
        a2 += __shfl_xor(a2, m);
        a3 += __shfl_xor(a3, m);
        ss += __shfl_xor(ss, m);
    }
    // Feature k (0..15) total lives in aq[k&3] of lane (k>>2). Lane index is a
    // compile-time constant (unrolled) -> v_readlane to SGPR, no DS traffic.
    float o = 0.f;
#pragma unroll
    for (int k = 0; k < 16; ++k) {
        float aqsel = (k & 3) == 0 ? a0 : ((k & 3) == 1 ? a1 : ((k & 3) == 2 ? a2 : a3));
        float rk = bcast_lane(aqsel, k >> 2);
        o += rk * W2[k * 64 + lane];               // coalesced W2 column
    }
    o = o / ss + b2[lane];                         // single normalize per node
    out[(size_t)node * 64 + lane] = o > 0.f ? o : 0.f;
}

extern "C" void kernel_launch(void* const* d_in, const int* in_sizes, int n_in,
                              void* d_out, int out_size, void* d_ws, size_t ws_size,
                              hipStream_t stream) {
    const float* x     = (const float*)d_in[0];
    const int*   ei    = (const int*)  d_in[1];
    const float* W1    = (const float*)d_in[2];
    const float* as1w  = (const float*)d_in[3];
    const float* ad1w  = (const float*)d_in[4];
    const float* b1    = (const float*)d_in[5];
    const float* W2    = (const float*)d_in[6];
    const float* as2w  = (const float*)d_in[7];
    const float* ad2w  = (const float*)d_in[8];
    const float* b2    = (const float*)d_in[9];
    float* out = (float*)d_out;

    // ws layout (4-byte elems, ~37 MB; 40.4 MB proven available):
    //   row_start[N+4] | csr_src[ETOT] | g[N*16 bf16, in former float slot] |
    //   asb[N] | adb[N] | as2b[N] | ad2b[N] | cvec[64] | pairs[ETOT] |
    //   H[M2] | off[M2] | bsum2[1024] | boff2[1024]
    int* row_start = (int*)d_ws;
    int* csr_src   = row_start + (NNODES + 4);
    float* gslot   = (float*)(csr_src + ETOT);   // N*16 floats reserved
    unsigned short* gbuf = (unsigned short*)gslot;  // N*16 bf16 used
    float* asb     = gslot + (size_t)NNODES * 16;
    float* adb     = asb + NNODES;
    float* as2b    = adb + NNODES;
    float* ad2b    = as2b + NNODES;
    float* cvec    = ad2b + NNODES;              // 36 floats used
    int* pairs     = (int*)(cvec + 64);          // ETOT
    int* H         = pairs + ETOT;               // M2
    int* off       = H + M2;                     // M2
    int* bsum2     = off + M2;                   // 1024
    int* boff2     = bsum2 + 1024;               // 1024

    const int B = 256;
    const int NB = (NNODES + B - 1) / B;

    // ---- CSR build: deterministic chunked bucket sort ----
    chunk_hist<<<NCHUNK, 1024, 0, stream>>>(ei, H);
    cscan_local<<<NSB2, 512, 0, stream>>>(H, off, bsum2);
    cscan_bsum<<<1, 1024, 0, stream>>>(bsum2, boff2);
    cscan_add<<<NSB2, 512, 0, stream>>>(off, boff2);
    chunk_scatter<<<NCHUNK, 1024, 0, stream>>>(ei, off, pairs);
    fine_sort2<<<NBUCK, B, 0, stream>>>(off, pairs, row_start, csr_src);

    // ---- attention precompute ----
    prep<<<1, 64, 0, stream>>>(W1, as1w, ad1w, W2, as2w, ad2w, cvec);

    // ---- Layer 1: alphas from x, aggregate x, W1 in epilogue (g stored bf16);
    //      layer-2 alphas fused into the epilogue (alpha2 kernel eliminated) ----
    alpha1<<<NB, B, 0, stream>>>(x, cvec, asb, adb);
    agg_l1<<<NNODES / 4, B, 0, stream>>>(row_start, csr_src, asb, adb, x, W1, b1,
                                         cvec, gbuf, as2b, ad2b);

    // ---- Layer 2: aggregate bf16 g, W2 in epilogue ----
    agg_l2<<<NNODES / 4, B, 0, stream>>>(row_start, csr_src, as2b, ad2b, gbuf, W2, b2, out);
}

// Round 4
// 242.544 us; speedup vs baseline: 1.1261x; 1.1261x over previous
//
#include <hip/hip_runtime.h>

#define NNODES 100000
#define NEDGES 3200000
#define ETOT   (NEDGES + NNODES)
#define NEG_SLOPE 0.2f

#define NPB 64                               // nodes per bucket (dst >> 6)
#define NBUCK ((NNODES + NPB - 1) / NPB)     // 1563 buckets
#define NCHUNK 256                           // edge chunks
#define CHUNK_E ((ETOT + NCHUNK - 1) / NCHUNK)  // 12891 edges/chunk
#define M2 (NBUCK * NCHUNK)                  // 400128 (chunk-scan length)
#define NSB2 ((M2 + 511) / 512)              // 782

// bf16 storage via raw ushort — no hip_fp16.h / hip_bf16.h dependency.
__device__ __forceinline__ unsigned short f2bf(float f) {
    unsigned u = __float_as_uint(f);
    u += 0x7FFFu + ((u >> 16) & 1u);         // round-to-nearest-even
    return (unsigned short)(u >> 16);
}
__device__ __forceinline__ float bf2f(unsigned short h) {
    return __uint_as_float(((unsigned)h) << 16);
}

// edge e in [0, NEDGES): src = ei[e], dst = ei[NEDGES+e]
// edge e in [NEDGES, ETOT): self-loop, src = dst = e - NEDGES
__device__ __forceinline__ void edge_sd(int e, const int* __restrict__ ei, int& s, int& d) {
    if (e < NEDGES) { s = ei[e]; d = ei[NEDGES + e]; }
    else            { s = e - NEDGES; d = s; }
}

__device__ __forceinline__ float lrelu(float v) {
    return v > 0.0f ? v : NEG_SLOPE * v;
}

// Broadcast from a compile-time lane: v_readlane -> SGPR (scalar pipe, no DS op).
__device__ __forceinline__ float bcast_lane(float v, int lane_imm) {
    return __int_as_float(__builtin_amdgcn_readlane(__float_as_int(v), lane_imm));
}

// ---------------- deterministic chunked bucket sort ----------------

__global__ void chunk_hist(const int* __restrict__ ei, int* __restrict__ H) {
    __shared__ int h[NBUCK];
    int c = blockIdx.x;
    for (int i = threadIdx.x; i < NBUCK; i += blockDim.x) h[i] = 0;
    __syncthreads();
    int lo = c * CHUNK_E, hi = lo + CHUNK_E; if (hi > ETOT) hi = ETOT;
    for (int e = lo + threadIdx.x; e < hi; e += blockDim.x) {
        int d = (e < NEDGES) ? ei[NEDGES + e] : (e - NEDGES);
        atomicAdd(&h[d >> 6], 1);
    }
    __syncthreads();
    for (int i = threadIdx.x; i < NBUCK; i += blockDim.x) H[c * NBUCK + i] = h[i];
}

// 3-phase exclusive scan of H in bucket-major order.
// Linear index i = b*NCHUNK + c (NCHUNK=256: b = i>>8, c = i&255); value = H[c*NBUCK+b].
__global__ void cscan_local(const int* __restrict__ H, int* __restrict__ off,
                            int* __restrict__ bsum2) {
    __shared__ int arr[512];
    int blk = blockIdx.x, t = threadIdx.x;
    int i = blk * 512 + t;
    int v = (i < M2) ? H[(i & (NCHUNK - 1)) * NBUCK + (i >> 8)] : 0;
    arr[t] = v;
    __syncthreads();
    for (int o = 1; o < 512; o <<= 1) {
        int u = (t >= o) ? arr[t - o] : 0;
        __syncthreads();
        arr[t] += u;
        __syncthreads();
    }
    if (i < M2) off[i] = arr[t] - v;
    if (t == 511) bsum2[blk] = arr[t];
}

__global__ void cscan_bsum(const int* __restrict__ bsum2, int* __restrict__ boff2) {
    __shared__ int arr[1024];
    int t = threadIdx.x;
    int v = (t < NSB2) ? bsum2[t] : 0;
    arr[t] = v;
    __syncthreads();
    for (int o = 1; o < 1024; o <<= 1) {
        int u = (t >= o) ? arr[t - o] : 0;
        __syncthreads();
        arr[t] += u;
        __syncthreads();
    }
    if (t < NSB2) boff2[t] = arr[t] - v;
}

__global__ void cscan_add(int* __restrict__ off, const int* __restrict__ boff2) {
    int i = blockIdx.x * 512 + threadIdx.x;
    if (i < M2) off[i] += boff2[blockIdx.x];
}

// Round-22 rewrite: LDS-staged scatter. The old version scattered 4B words
// directly to HBM across ~64 bucket segments per wave (avg segment 33B) ->
// WRITE_SIZE 67-78MB for a 13.2MB payload (5-6x amplification), 57-59us,
// VALUBusy 1.9%. Now: scan the chunk's histogram row (H) for local compaction,
// scatter into LDS (98KB: whole chunk), copy out linearly -- entry at local
// slot i of bucket b lands at gbase[b]+i, so consecutive slots are consecutive
// addresses (burst-coalesced per segment). Grid is 256 blocks = 1/CU, so the
// big LDS costs no occupancy.
__global__ __launch_bounds__(1024)
void chunk_scatter(const int* __restrict__ ei, const int* __restrict__ off,
                   const int* __restrict__ H, int* __restrict__ pairs) {
    __shared__ int plds[CHUNK_E];            // 51564 B: packed pair per local slot
    __shared__ unsigned short blds[CHUNK_E]; // 25782 B: bucket id per local slot
    __shared__ int sc[2048];                 //  8192 B: inclusive scan of counts
    __shared__ int lcur[NBUCK];              //  6252 B: local alloc cursor
    __shared__ int gbase[NBUCK];             //  6252 B: off[b,c] - lpref[b]
    int c = blockIdx.x, t = threadIdx.x;
    // load this chunk's bucket counts
    for (int b = t; b < 2048; b += 1024) sc[b] = (b < NBUCK) ? H[c * NBUCK + b] : 0;
    __syncthreads();
    // Hillis-Steele inclusive scan over 2048 entries, 2 per thread
    for (int o = 1; o < 2048; o <<= 1) {
        int i1 = t + 1024;
        int v0 = (t >= o) ? sc[t - o] : 0;
        int v1 = (i1 >= o) ? sc[i1 - o] : 0;
        __syncthreads();
        sc[t] += v0; sc[i1] += v1;
        __syncthreads();
    }
    for (int b = t; b < NBUCK; b += 1024) {
        int excl = (b == 0) ? 0 : sc[b - 1];        // exclusive local prefix
        lcur[b]  = excl;
        gbase[b] = off[b * NCHUNK + c] - excl;
    }
    __syncthreads();
    int lo = c * CHUNK_E, hi = lo + CHUNK_E; if (hi > ETOT) hi = ETOT;
    int n = hi - lo;
    for (int e = lo + t; e < hi; e += 1024) {
        int s, d; edge_sd(e, ei, s, d);
        int b = d >> 6;
        int slot = atomicAdd(&lcur[b], 1);
        plds[slot] = ((d & 63) << 17) | s;          // src < 2^17
        blds[slot] = (unsigned short)b;
    }
    __syncthreads();
    for (int i = t; i < n; i += 1024)
        pairs[gbase[blds[i]] + i] = plds[i];        // coalesced within segments
}

__global__ void fine_sort2(const int* __restrict__ off, const int* __restrict__ pairs,
                           int* __restrict__ row_start, int* __restrict__ csr_src) {
    __shared__ int arr[NPB];
    __shared__ int cur[NPB];
    int b = blockIdx.x;
    int t = threadIdx.x;
    int base = off[b * NCHUNK];
    int bend = (b == NBUCK - 1) ? ETOT : off[(b + 1) * NCHUNK];
    if (t < NPB) arr[t] = 0;
    __syncthreads();
    for (int i = base + t; i < bend; i += blockDim.x)
        atomicAdd(&arr[pairs[i] >> 17], 1);
    __syncthreads();
    int v = (t < NPB) ? arr[t] : 0;
    __syncthreads();
    for (int o = 1; o < NPB; o <<= 1) {           // inclusive scan over 64 counts
        int u = (t < NPB && t >= o) ? arr[t - o] : 0;
        __syncthreads();
        if (t < NPB) arr[t] += u;
        __syncthreads();
    }
    if (t < NPB) {
        int node = b * NPB + t;
        int start = base + arr[t] - v;            // exclusive prefix
        cur[t] = start;
        if (node < NNODES) row_start[node] = start;
    }
    if (b == NBUCK - 1 && t == 0) row_start[NNODES] = ETOT;
    __syncthreads();
    for (int i = base + t; i < bend; i += blockDim.x) {
        int p = pairs[i];
        int slot = atomicAdd(&cur[p >> 17], 1);
        csr_src[slot] = p & 0x1FFFF;
    }
}

// ---------------- attention-vector precompute (proven) ----------------
// cvec layout: [0,1]=c1s  [2,3]=c1d  [4..19]=c2s  [20..35]=c2d
__global__ void prep(const float* __restrict__ W1, const float* __restrict__ as1,
                     const float* __restrict__ ad1, const float* __restrict__ W2,
                     const float* __restrict__ as2, const float* __restrict__ ad2,
                     float* __restrict__ cvec) {
    int t = threadIdx.x;
    if (t < 2) {
        float s = 0.f, d = 0.f;
        for (int f = 0; f < 16; ++f) { s += W1[t * 16 + f] * as1[f]; d += W1[t * 16 + f] * ad1[f]; }
        cvec[t] = s; cvec[2 + t] = d;
    }
    if (t < 16) {
        float s = 0.f, d = 0.f;
        for (int f = 0; f < 64; ++f) { s += W2[t * 64 + f] * as2[f]; d += W2[t * 64 + f] * ad2[f]; }
        cvec[4 + t] = s; cvec[20 + t] = d;
    }
}

__global__ void alpha1(const float* __restrict__ x, const float* __restrict__ cvec,
                       float* __restrict__ as_, float* __restrict__ ad_) {
    int n = blockIdx.x * blockDim.x + threadIdx.x;
    if (n >= NNODES) return;
    float2 xv = ((const float2*)x)[n];
    as_[n] = xv.x * cvec[0] + xv.y * cvec[1];
    ad_[n] = xv.x * cvec[2] + xv.y * cvec[3];
}

// ---------------- layer 1: aggregate x (2 feats), @W1 in epilogue -------------
// In-register __shfl_xor butterfly; zero LDS, zero barriers. 256-thread blocks.
// Edge loop software-pipelined (prefetch next sj/as_/x with clamped index);
// alpha2 fused into the epilogue (layer-2 alpha dot products via 8 shfl_xor).
__global__ void agg_l1(const int* __restrict__ row_start, const int* __restrict__ csr_src,
                       const float* __restrict__ as_, const float* __restrict__ ad_,
                       const float* __restrict__ x, const float* __restrict__ W1,
                       const float* __restrict__ b1, const float* __restrict__ cvec,
                       unsigned short* __restrict__ g,
                       float* __restrict__ as2_, float* __restrict__ ad2_) {
    int wave = threadIdx.x >> 6, lane = threadIdx.x & 63;
    int node = blockIdx.x * 4 + wave;          // always < NNODES (exact grid)
    int base = row_start[node], end = row_start[node + 1];
    float adv = ad_[node];
    float a0 = 0.f, a1 = 0.f, ss = 0.f;
    const float2* x2 = (const float2*)x;
    int last = end - 1;                        // end > base always (self-loop)
    int i = base + lane;
    int sj = csr_src[min(i, last)];
    float asv = as_[sj];
    float2 xv = x2[sj];
    while (i < end) {
        int inext = i + 64;
        int sjn = csr_src[min(inext, last)];   // prefetch next iteration
        float asn = as_[sjn];
        float2 xn = x2[sjn];
        float w = __expf(lrelu(asv + adv));
        ss += w;
        a0 += w * xv.x;
        a1 += w * xv.y;
        i = inext; sj = sjn; asv = asn; xv = xn;
    }
#pragma unroll
    for (int m = 32; m >= 1; m >>= 1) {        // full 64-lane butterfly
        a0 += __shfl_xor(a0, m);
        a1 += __shfl_xor(a1, m);
        ss += __shfl_xor(ss, m);
    }
    int f = lane & 15;                         // all lanes compute feature f
    float v = (a0 * W1[f] + a1 * W1[16 + f]) / ss + b1[f];
    float vr = v > 0.f ? v : 0.f;
    if (lane < 16) g[node * 16 + lane] = f2bf(vr);
    // fused alpha2 (f32, closer to reference than bf16 round-trip)
    float s2 = vr * cvec[4 + f];
    float d2 = vr * cvec[20 + f];
#pragma unroll
    for (int m = 1; m <= 8; m <<= 1) {
        s2 += __shfl_xor(s2, m);
        d2 += __shfl_xor(d2, m);
    }
    if (lane == 0) { as2_[node] = s2; ad2_[node] = d2; }
}

// ---------------- layer 2: aggregate bf16 g, @W2 in epilogue ------------------
// 16 groups x 4 lanes; each lane loads a ushort4 (8B) of the 32B row -> 16 rows
// in flight. Butterfly over group bits (masks 4..32) via __shfl_xor; feature
// broadcast via v_readlane (compile-time lane). 256-thread blocks (proven).
// Edge loop software-pipelined (prefetch next sj/as_/g-row, clamped index).
__global__ void agg_l2(const int* __restrict__ row_start, const int* __restrict__ csr_src,
                       const float* __restrict__ as_, const float* __restrict__ ad_,
                       const unsigned short* __restrict__ g, const float* __restrict__ W2,
                       const float* __restrict__ b2, float* __restrict__ out) {
    int wave = threadIdx.x >> 6, lane = threadIdx.x & 63;
    int grp = lane >> 2;              // 0..15: edge group
    int q   = lane & 3;               // 0..3:  feature quad (features q*4..q*4+3)
    int node = blockIdx.x * 4 + wave; // always < NNODES (exact grid)
    int base = row_start[node], end = row_start[node + 1];
    float adv = ad_[node];
    float a0 = 0.f, a1 = 0.f, a2 = 0.f, a3 = 0.f, ss = 0.f;
    int last = end - 1;
    int i = base + grp;
    int sj = csr_src[min(i, last)];           // uniform within 4-lane group
    float asv = as_[sj];
    ushort4 hv = ((const ushort4*)(g + sj * 16))[q];
    while (i < end) {
        int inext = i + 16;
        int sjn = csr_src[min(inext, last)];  // prefetch next iteration
        float asn = as_[sjn];
        ushort4 hn = ((const ushort4*)(g + sjn * 16))[q];
        float w = __expf(lrelu(asv + adv));
        ss += w;
        a0 += w * bf2f(hv.x);
        a1 += w * bf2f(hv.y);
        a2 += w * bf2f(hv.z);
        a3 += w * bf2f(hv.w);
        i = inext; sj = sjn; asv = asn; hv = hn;
    }
    // Butterfly over group bits (masks 4,8,16,32): lane l ends with the total
    // over all 16 groups for its quad q = l&3. ss identical across lanes.
#pragma unroll
    for (int m = 4; m <= 32; m <<= 1) {
        a0 += __shfl_xor(a0, m);
        a1 += __shfl_xor(a1, m);
        a2 += __shfl_xor(a2, m);
        a3 += __shfl_xor(a3, m);
        ss += __shfl_xor(ss, m);
    }
    // Feature k (0..15) total lives in aq[k&3] of lane (k>>2). Lane index is a
    // compile-time constant (unrolled) -> v_readlane to SGPR, no DS traffic.
    float o = 0.f;
#pragma unroll
    for (int k = 0; k < 16; ++k) {
        float aqsel = (k & 3) == 0 ? a0 : ((k & 3) == 1 ? a1 : ((k & 3) == 2 ? a2 : a3));
        float rk = bcast_lane(aqsel, k >> 2);
        o += rk * W2[k * 64 + lane];               // coalesced W2 column
    }
    o = o / ss + b2[lane];                         // single normalize per node
    out[(size_t)node * 64 + lane] = o > 0.f ? o : 0.f;
}

extern "C" void kernel_launch(void* const* d_in, const int* in_sizes, int n_in,
                              void* d_out, int out_size, void* d_ws, size_t ws_size,
                              hipStream_t stream) {
    const float* x     = (const float*)d_in[0];
    const int*   ei    = (const int*)  d_in[1];
    const float* W1    = (const float*)d_in[2];
    const float* as1w  = (const float*)d_in[3];
    const float* ad1w  = (const float*)d_in[4];
    const float* b1    = (const float*)d_in[5];
    const float* W2    = (const float*)d_in[6];
    const float* as2w  = (const float*)d_in[7];
    const float* ad2w  = (const float*)d_in[8];
    const float* b2    = (const float*)d_in[9];
    float* out = (float*)d_out;

    // ws layout (4-byte elems, ~37 MB; 40.4 MB proven available):
    //   row_start[N+4] | csr_src[ETOT] | g[N*16 bf16, in former float slot] |
    //   asb[N] | adb[N] | as2b[N] | ad2b[N] | cvec[64] | pairs[ETOT] |
    //   H[M2] | off[M2] | bsum2[1024] | boff2[1024]
    int* row_start = (int*)d_ws;
    int* csr_src   = row_start + (NNODES + 4);
    float* gslot   = (float*)(csr_src + ETOT);   // N*16 floats reserved
    unsigned short* gbuf = (unsigned short*)gslot;  // N*16 bf16 used
    float* asb     = gslot + (size_t)NNODES * 16;
    float* adb     = asb + NNODES;
    float* as2b    = adb + NNODES;
    float* ad2b    = as2b + NNODES;
    float* cvec    = ad2b + NNODES;              // 36 floats used
    int* pairs     = (int*)(cvec + 64);          // ETOT
    int* H         = pairs + ETOT;               // M2
    int* off       = H + M2;                     // M2
    int* bsum2     = off + M2;                   // 1024
    int* boff2     = bsum2 + 1024;               // 1024

    const int B = 256;
    const int NB = (NNODES + B - 1) / B;

    // ---- CSR build: deterministic chunked bucket sort ----
    chunk_hist<<<NCHUNK, 1024, 0, stream>>>(ei, H);
    cscan_local<<<NSB2, 512, 0, stream>>>(H, off, bsum2);
    cscan_bsum<<<1, 1024, 0, stream>>>(bsum2, boff2);
    cscan_add<<<NSB2, 512, 0, stream>>>(off, boff2);
    chunk_scatter<<<NCHUNK, 1024, 0, stream>>>(ei, off, H, pairs);
    fine_sort2<<<NBUCK, B, 0, stream>>>(off, pairs, row_start, csr_src);

    // ---- attention precompute ----
    prep<<<1, 64, 0, stream>>>(W1, as1w, ad1w, W2, as2w, ad2w, cvec);

    // ---- Layer 1: alphas from x, aggregate x, W1 in epilogue (g stored bf16);
    //      layer-2 alphas fused into the epilogue (alpha2 kernel eliminated) ----
    alpha1<<<NB, B, 0, stream>>>(x, cvec, asb, adb);
    agg_l1<<<NNODES / 4, B, 0, stream>>>(row_start, csr_src, asb, adb, x, W1, b1,
                                         cvec, gbuf, as2b, ad2b);

    // ---- Layer 2: aggregate bf16 g, W2 in epilogue ----
    agg_l2<<<NNODES / 4, B, 0, stream>>>(row_start, csr_src, as2b, ad2b, gbuf, W2, b2, out);
}

// Round 5
// 240.559 us; speedup vs baseline: 1.1354x; 1.0083x over previous
//
#include <hip/hip_runtime.h>

#define NNODES 100000
#define NEDGES 3200000
#define ETOT   (NEDGES + NNODES)
#define NEG_SLOPE 0.2f

#define NPB 64                               // nodes per bucket (dst >> 6)
#define NBUCK ((NNODES + NPB - 1) / NPB)     // 1563 buckets
#define NCHUNK 256                           // edge chunks
#define CHUNK_E ((ETOT + NCHUNK - 1) / NCHUNK)  // 12891 edges/chunk
#define M2 (NBUCK * NCHUNK)                  // 400128 (chunk-scan length)
#define NSB2 ((M2 + 511) / 512)              // 782

// bf16 storage via raw ushort — no hip_fp16.h / hip_bf16.h dependency.
__device__ __forceinline__ unsigned short f2bf(float f) {
    unsigned u = __float_as_uint(f);
    u += 0x7FFFu + ((u >> 16) & 1u);         // round-to-nearest-even
    return (unsigned short)(u >> 16);
}
__device__ __forceinline__ float bf2f(unsigned short h) {
    return __uint_as_float(((unsigned)h) << 16);
}

// edge e in [0, NEDGES): src = ei[e], dst = ei[NEDGES+e]
// edge e in [NEDGES, ETOT): self-loop, src = dst = e - NEDGES
__device__ __forceinline__ void edge_sd(int e, const int* __restrict__ ei, int& s, int& d) {
    if (e < NEDGES) { s = ei[e]; d = ei[NEDGES + e]; }
    else            { s = e - NEDGES; d = s; }
}

__device__ __forceinline__ float lrelu(float v) {
    return v > 0.0f ? v : NEG_SLOPE * v;
}

// Broadcast from a compile-time lane: v_readlane -> SGPR (scalar pipe, no DS op).
__device__ __forceinline__ float bcast_lane(float v, int lane_imm) {
    return __int_as_float(__builtin_amdgcn_readlane(__float_as_int(v), lane_imm));
}

// ---- Round-23: reduction primitives without generic __shfl_xor lowering ----
// For SUMS, in-row (16-lane) exchange can be a DPP row rotation fused into the
// add (pure VALU, no lane-id math, no DS op). row_ror:N ctrl = 0x120+N.
template<int CTRL>
__device__ __forceinline__ float dpp_add(float v) {
    return v + __int_as_float(__builtin_amdgcn_mov_dpp(__float_as_int(v), CTRL, 0xF, 0xF, true));
}
// Cross-row within a 32-lane half: ds_swizzle xor-16 (offset 0x401F).
__device__ __forceinline__ float swz16_add(float v) {
    return v + __int_as_float(__builtin_amdgcn_ds_swizzle(__float_as_int(v), 0x401F));
}
// Sum over all 16 lanes of each row (rotations 1,2,4,8).
__device__ __forceinline__ float row16_sum(float v) {
    v = dpp_add<0x121>(v);   // row_ror:1
    v = dpp_add<0x122>(v);   // row_ror:2
    v = dpp_add<0x124>(v);   // row_ror:4
    v = dpp_add<0x128>(v);   // row_ror:8
    return v;
}

// ---------------- deterministic chunked bucket sort ----------------

__global__ void chunk_hist(const int* __restrict__ ei, int* __restrict__ H) {
    __shared__ int h[NBUCK];
    int c = blockIdx.x;
    for (int i = threadIdx.x; i < NBUCK; i += blockDim.x) h[i] = 0;
    __syncthreads();
    int lo = c * CHUNK_E, hi = lo + CHUNK_E; if (hi > ETOT) hi = ETOT;
    for (int e = lo + threadIdx.x; e < hi; e += blockDim.x) {
        int d = (e < NEDGES) ? ei[NEDGES + e] : (e - NEDGES);
        atomicAdd(&h[d >> 6], 1);
    }
    __syncthreads();
    for (int i = threadIdx.x; i < NBUCK; i += blockDim.x) H[c * NBUCK + i] = h[i];
}

// 3-phase exclusive scan of H in bucket-major order.
// Linear index i = b*NCHUNK + c (NCHUNK=256: b = i>>8, c = i&255); value = H[c*NBUCK+b].
__global__ void cscan_local(const int* __restrict__ H, int* __restrict__ off,
                            int* __restrict__ bsum2) {
    __shared__ int arr[512];
    int blk = blockIdx.x, t = threadIdx.x;
    int i = blk * 512 + t;
    int v = (i < M2) ? H[(i & (NCHUNK - 1)) * NBUCK + (i >> 8)] : 0;
    arr[t] = v;
    __syncthreads();
    for (int o = 1; o < 512; o <<= 1) {
        int u = (t >= o) ? arr[t - o] : 0;
        __syncthreads();
        arr[t] += u;
        __syncthreads();
    }
    if (i < M2) off[i] = arr[t] - v;
    if (t == 511) bsum2[blk] = arr[t];
}

__global__ void cscan_bsum(const int* __restrict__ bsum2, int* __restrict__ boff2) {
    __shared__ int arr[1024];
    int t = threadIdx.x;
    int v = (t < NSB2) ? bsum2[t] : 0;
    arr[t] = v;
    __syncthreads();
    for (int o = 1; o < 1024; o <<= 1) {
        int u = (t >= o) ? arr[t - o] : 0;
        __syncthreads();
        arr[t] += u;
        __syncthreads();
    }
    if (t < NSB2) boff2[t] = arr[t] - v;
}

__global__ void cscan_add(int* __restrict__ off, const int* __restrict__ boff2) {
    int i = blockIdx.x * 512 + threadIdx.x;
    if (i < M2) off[i] += boff2[blockIdx.x];
}

// LDS-staged scatter (round-22, proven: WRITE_SIZE 67-78MB -> off top-5).
// Scan the chunk's histogram row for local compaction, scatter into LDS (98KB),
// copy out linearly -- entry at local slot i of bucket b lands at gbase[b]+i.
// Grid is 256 blocks = 1/CU, so the big LDS costs no occupancy.
__global__ __launch_bounds__(1024)
void chunk_scatter(const int* __restrict__ ei, const int* __restrict__ off,
                   const int* __restrict__ H, int* __restrict__ pairs) {
    __shared__ int plds[CHUNK_E];            // 51564 B: packed pair per local slot
    __shared__ unsigned short blds[CHUNK_E]; // 25782 B: bucket id per local slot
    __shared__ int sc[2048];                 //  8192 B: inclusive scan of counts
    __shared__ int lcur[NBUCK];              //  6252 B: local alloc cursor
    __shared__ int gbase[NBUCK];             //  6252 B: off[b,c] - lpref[b]
    int c = blockIdx.x, t = threadIdx.x;
    // load this chunk's bucket counts
    for (int b = t; b < 2048; b += 1024) sc[b] = (b < NBUCK) ? H[c * NBUCK + b] : 0;
    __syncthreads();
    // Hillis-Steele inclusive scan over 2048 entries, 2 per thread
    for (int o = 1; o < 2048; o <<= 1) {
        int i1 = t + 1024;
        int v0 = (t >= o) ? sc[t - o] : 0;
        int v1 = (i1 >= o) ? sc[i1 - o] : 0;
        __syncthreads();
        sc[t] += v0; sc[i1] += v1;
        __syncthreads();
    }
    for (int b = t; b < NBUCK; b += 1024) {
        int excl = (b == 0) ? 0 : sc[b - 1];        // exclusive local prefix
        lcur[b]  = excl;
        gbase[b] = off[b * NCHUNK + c] - excl;
    }
    __syncthreads();
    int lo = c * CHUNK_E, hi = lo + CHUNK_E; if (hi > ETOT) hi = ETOT;
    int n = hi - lo;
    for (int e = lo + t; e < hi; e += 1024) {
        int s, d; edge_sd(e, ei, s, d);
        int b = d >> 6;
        int slot = atomicAdd(&lcur[b], 1);
        plds[slot] = ((d & 63) << 17) | s;          // src < 2^17
        blds[slot] = (unsigned short)b;
    }
    __syncthreads();
    for (int i = t; i < n; i += 1024)
        pairs[gbase[blds[i]] + i] = plds[i];        // coalesced within segments
}

__global__ void fine_sort2(const int* __restrict__ off, const int* __restrict__ pairs,
                           int* __restrict__ row_start, int* __restrict__ csr_src) {
    __shared__ int arr[NPB];
    __shared__ int cur[NPB];
    int b = blockIdx.x;
    int t = threadIdx.x;
    int base = off[b * NCHUNK];
    int bend = (b == NBUCK - 1) ? ETOT : off[(b + 1) * NCHUNK];
    if (t < NPB) arr[t] = 0;
    __syncthreads();
    for (int i = base + t; i < bend; i += blockDim.x)
        atomicAdd(&arr[pairs[i] >> 17], 1);
    __syncthreads();
    int v = (t < NPB) ? arr[t] : 0;
    __syncthreads();
    for (int o = 1; o < NPB; o <<= 1) {           // inclusive scan over 64 counts
        int u = (t < NPB && t >= o) ? arr[t - o] : 0;
        __syncthreads();
        if (t < NPB) arr[t] += u;
        __syncthreads();
    }
    if (t < NPB) {
        int node = b * NPB + t;
        int start = base + arr[t] - v;            // exclusive prefix
        cur[t] = start;
        if (node < NNODES) row_start[node] = start;
    }
    if (b == NBUCK - 1 && t == 0) row_start[NNODES] = ETOT;
    __syncthreads();
    for (int i = base + t; i < bend; i += blockDim.x) {
        int p = pairs[i];
        int slot = atomicAdd(&cur[p >> 17], 1);
        csr_src[slot] = p & 0x1FFFF;
    }
}

// ---------------- attention-vector precompute (proven) ----------------
// cvec layout: [0,1]=c1s  [2,3]=c1d  [4..19]=c2s  [20..35]=c2d
__global__ void prep(const float* __restrict__ W1, const float* __restrict__ as1,
                     const float* __restrict__ ad1, const float* __restrict__ W2,
                     const float* __restrict__ as2, const float* __restrict__ ad2,
                     float* __restrict__ cvec) {
    int t = threadIdx.x;
    if (t < 2) {
        float s = 0.f, d = 0.f;
        for (int f = 0; f < 16; ++f) { s += W1[t * 16 + f] * as1[f]; d += W1[t * 16 + f] * ad1[f]; }
        cvec[t] = s; cvec[2 + t] = d;
    }
    if (t < 16) {
        float s = 0.f, d = 0.f;
        for (int f = 0; f < 64; ++f) { s += W2[t * 64 + f] * as2[f]; d += W2[t * 64 + f] * ad2[f]; }
        cvec[4 + t] = s; cvec[20 + t] = d;
    }
}

__global__ void alpha1(const float* __restrict__ x, const float* __restrict__ cvec,
                       float* __restrict__ as_, float* __restrict__ ad_) {
    int n = blockIdx.x * blockDim.x + threadIdx.x;
    if (n >= NNODES) return;
    float2 xv = ((const float2*)x)[n];
    as_[n] = xv.x * cvec[0] + xv.y * cvec[1];
    ad_[n] = xv.x * cvec[2] + xv.y * cvec[3];
}

// ---------------- layer 1: aggregate x (2 feats), @W1 in epilogue -------------
// Zero LDS, zero barriers; 256-thread blocks; software-pipelined edge loop;
// alpha2 fused in epilogue. Round-23: generic __shfl_xor butterfly replaced by
// DPP row-rotation adds (masks 1..8, pure VALU) + ds_swizzle xor16 + one
// __shfl_xor(32) — cuts ~16 DS ops + lane-addr VALU per wave. The fused
// alpha2 reduce is row-local (features 0..15 live in each 16-lane row) -> 4
// DPP adds per value, zero DS.
__global__ void agg_l1(const int* __restrict__ row_start, const int* __restrict__ csr_src,
                       const float* __restrict__ as_, const float* __restrict__ ad_,
                       const float* __restrict__ x, const float* __restrict__ W1,
                       const float* __restrict__ b1, const float* __restrict__ cvec,
                       unsigned short* __restrict__ g,
                       float* __restrict__ as2_, float* __restrict__ ad2_) {
    int wave = threadIdx.x >> 6, lane = threadIdx.x & 63;
    int node = blockIdx.x * 4 + wave;          // always < NNODES (exact grid)
    int base = row_start[node], end = row_start[node + 1];
    float adv = ad_[node];
    float a0 = 0.f, a1 = 0.f, ss = 0.f;
    const float2* x2 = (const float2*)x;
    int last = end - 1;                        // end > base always (self-loop)
    int i = base + lane;
    int sj = csr_src[min(i, last)];
    float asv = as_[sj];
    float2 xv = x2[sj];
    while (i < end) {
        int inext = i + 64;
        int sjn = csr_src[min(inext, last)];   // prefetch next iteration
        float asn = as_[sjn];
        float2 xn = x2[sjn];
        float w = __expf(lrelu(asv + adv));
        ss += w;
        a0 += w * xv.x;
        a1 += w * xv.y;
        i = inext; sj = sjn; asv = asn; xv = xn;
    }
    // full 64-lane sum: 4 DPP rotations (in-row) + swizzle16 + shfl32
    a0 = row16_sum(a0); a1 = row16_sum(a1); ss = row16_sum(ss);
    a0 = swz16_add(a0); a1 = swz16_add(a1); ss = swz16_add(ss);
    a0 += __shfl_xor(a0, 32);
    a1 += __shfl_xor(a1, 32);
    ss += __shfl_xor(ss, 32);
    int f = lane & 15;                         // all lanes compute feature f
    float v = (a0 * W1[f] + a1 * W1[16 + f]) / ss + b1[f];
    float vr = v > 0.f ? v : 0.f;
    if (lane < 16) g[node * 16 + lane] = f2bf(vr);
    // fused alpha2 (f32): sum over the 16 features of this row (row-local)
    float s2 = vr * cvec[4 + f];
    float d2 = vr * cvec[20 + f];
    s2 = row16_sum(s2); d2 = row16_sum(d2);
    if (lane == 0) { as2_[node] = s2; ad2_[node] = d2; }
}

// ---------------- layer 2: aggregate bf16 g, @W2 in epilogue ------------------
// 16 groups x 4 lanes; each lane loads a ushort4 (8B) of the 32B row -> 16 rows
// in flight. 256-thread blocks; software-pipelined edge loop; readlane
// broadcast epilogue. Round-23: group reduction (lane bits 2..5) via DPP
// row_ror:4 + row_ror:8 (q = lane&3 preserved by rotation step 4) + swizzle16
// + one __shfl_xor(32) — 20 generic shuffles -> 10 DS ops, ~80 fewer VALU.
__global__ void agg_l2(const int* __restrict__ row_start, const int* __restrict__ csr_src,
                       const float* __restrict__ as_, const float* __restrict__ ad_,
                       const unsigned short* __restrict__ g, const float* __restrict__ W2,
                       const float* __restrict__ b2, float* __restrict__ out) {
    int wave = threadIdx.x >> 6, lane = threadIdx.x & 63;
    int grp = lane >> 2;              // 0..15: edge group
    int q   = lane & 3;               // 0..3:  feature quad (features q*4..q*4+3)
    int node = blockIdx.x * 4 + wave; // always < NNODES (exact grid)
    int base = row_start[node], end = row_start[node + 1];
    float adv = ad_[node];
    float a0 = 0.f, a1 = 0.f, a2 = 0.f, a3 = 0.f, ss = 0.f;
    int last = end - 1;
    int i = base + grp;
    int sj = csr_src[min(i, last)];           // uniform within 4-lane group
    float asv = as_[sj];
    ushort4 hv = ((const ushort4*)(g + sj * 16))[q];
    while (i < end) {
        int inext = i + 16;
        int sjn = csr_src[min(inext, last)];  // prefetch next iteration
        float asn = as_[sjn];
        ushort4 hn = ((const ushort4*)(g + sjn * 16))[q];
        float w = __expf(lrelu(asv + adv));
        ss += w;
        a0 += w * bf2f(hv.x);
        a1 += w * bf2f(hv.y);
        a2 += w * bf2f(hv.z);
        a3 += w * bf2f(hv.w);
        i = inext; sj = sjn; asv = asn; hv = hn;
    }
    // Reduce over group bits. In-row groups (bits 2,3): rotations by 4 and 8
    // preserve q = lane&3. Cross-row: swizzle xor16, then shfl xor32.
    a0 = dpp_add<0x124>(a0); a1 = dpp_add<0x124>(a1);
    a2 = dpp_add<0x124>(a2); a3 = dpp_add<0x124>(a3); ss = dpp_add<0x124>(ss);
    a0 = dpp_add<0x128>(a0); a1 = dpp_add<0x128>(a1);
    a2 = dpp_add<0x128>(a2); a3 = dpp_add<0x128>(a3); ss = dpp_add<0x128>(ss);
    a0 = swz16_add(a0); a1 = swz16_add(a1);
    a2 = swz16_add(a2); a3 = swz16_add(a3); ss = swz16_add(ss);
    a0 += __shfl_xor(a0, 32);
    a1 += __shfl_xor(a1, 32);
    a2 += __shfl_xor(a2, 32);
    a3 += __shfl_xor(a3, 32);
    ss += __shfl_xor(ss, 32);
    // Feature k (0..15) total lives in aq[k&3] of lane (k>>2). Lane index is a
    // compile-time constant (unrolled) -> v_readlane to SGPR, no DS traffic.
    float o = 0.f;
#pragma unroll
    for (int k = 0; k < 16; ++k) {
        float aqsel = (k & 3) == 0 ? a0 : ((k & 3) == 1 ? a1 : ((k & 3) == 2 ? a2 : a3));
        float rk = bcast_lane(aqsel, k >> 2);
        o += rk * W2[k * 64 + lane];               // coalesced W2 column
    }
    o = o / ss + b2[lane];                         // single normalize per node
    out[(size_t)node * 64 + lane] = o > 0.f ? o : 0.f;
}

extern "C" void kernel_launch(void* const* d_in, const int* in_sizes, int n_in,
                              void* d_out, int out_size, void* d_ws, size_t ws_size,
                              hipStream_t stream) {
    const float* x     = (const float*)d_in[0];
    const int*   ei    = (const int*)  d_in[1];
    const float* W1    = (const float*)d_in[2];
    const float* as1w  = (const float*)d_in[3];
    const float* ad1w  = (const float*)d_in[4];
    const float* b1    = (const float*)d_in[5];
    const float* W2    = (const float*)d_in[6];
    const float* as2w  = (const float*)d_in[7];
    const float* ad2w  = (const float*)d_in[8];
    const float* b2    = (const float*)d_in[9];
    float* out = (float*)d_out;

    // ws layout (4-byte elems, ~37 MB; 40.4 MB proven available):
    //   row_start[N+4] | csr_src[ETOT] | g[N*16 bf16, in former float slot] |
    //   asb[N] | adb[N] | as2b[N] | ad2b[N] | cvec[64] | pairs[ETOT] |
    //   H[M2] | off[M2] | bsum2[1024] | boff2[1024]
    int* row_start = (int*)d_ws;
    int* csr_src   = row_start + (NNODES + 4);
    float* gslot   = (float*)(csr_src + ETOT);   // N*16 floats reserved
    unsigned short* gbuf = (unsigned short*)gslot;  // N*16 bf16 used
    float* asb     = gslot + (size_t)NNODES * 16;
    float* adb     = asb + NNODES;
    float* as2b    = adb + NNODES;
    float* ad2b    = as2b + NNODES;
    float* cvec    = ad2b + NNODES;              // 36 floats used
    int* pairs     = (int*)(cvec + 64);          // ETOT
    int* H         = pairs + ETOT;               // M2
    int* off       = H + M2;                     // M2
    int* bsum2     = off + M2;                   // 1024
    int* boff2     = bsum2 + 1024;               // 1024

    const int B = 256;
    const int NB = (NNODES + B - 1) / B;

    // ---- CSR build: deterministic chunked bucket sort ----
    chunk_hist<<<NCHUNK, 1024, 0, stream>>>(ei, H);
    cscan_local<<<NSB2, 512, 0, stream>>>(H, off, bsum2);
    cscan_bsum<<<1, 1024, 0, stream>>>(bsum2, boff2);
    cscan_add<<<NSB2, 512, 0, stream>>>(off, boff2);
    chunk_scatter<<<NCHUNK, 1024, 0, stream>>>(ei, off, H, pairs);
    fine_sort2<<<NBUCK, B, 0, stream>>>(off, pairs, row_start, csr_src);

    // ---- attention precompute ----
    prep<<<1, 64, 0, stream>>>(W1, as1w, ad1w, W2, as2w, ad2w, cvec);

    // ---- Layer 1: alphas from x, aggregate x, W1 in epilogue (g stored bf16);
    //      layer-2 alphas fused into the epilogue (alpha2 kernel eliminated) ----
    alpha1<<<NB, B, 0, stream>>>(x, cvec, asb, adb);
    agg_l1<<<NNODES / 4, B, 0, stream>>>(row_start, csr_src, asb, adb, x, W1, b1,
                                         cvec, gbuf, as2b, ad2b);

    // ---- Layer 2: aggregate bf16 g, W2 in epilogue ----
    agg_l2<<<NNODES / 4, B, 0, stream>>>(row_start, csr_src, as2b, ad2b, gbuf, W2, b2, out);
}